// Round 1
// baseline (260.064 us; speedup 1.0000x reference)
//
#include <hip/hip_runtime.h>
#include <math.h>

#define T_FRAMES 16384
#define FDIM 2048
#define LQ 30

// ---------------------------------------------------------------------------
// Kernel 0: precompute per-head 7x7 bilinear forms
//   A_h[c][c2] = sum_d W_q[h*64+d][c] * W_k[h*64+d][c2]   (score bilinear form)
//   M_h[c][c2] = sum_d W_o[c][h*64+d] * W_v[h*64+d][c2]   (output projection of
//                                                          weighted feats sum)
// AM layout: [0..195] = A (h*49 + c*7 + c2), [196..391] = M
// ---------------------------------------------------------------------------
__global__ __launch_bounds__(448) void setup_kernel(
    const float* __restrict__ Wq, const float* __restrict__ Wk,
    const float* __restrict__ Wv, const float* __restrict__ Wo,
    float* __restrict__ AM) {
  const int e = threadIdx.x;
  if (e >= 392) return;
  const int which = e / 196;          // 0 = A, 1 = M
  const int r = e % 196;
  const int h = r / 49;
  const int rr = r % 49;
  const int c = rr / 7;
  const int c2 = rr % 7;
  float s = 0.0f;
  if (which == 0) {
    for (int d = 0; d < 64; ++d)
      s = fmaf(Wq[(h * 64 + d) * 7 + c], Wk[(h * 64 + d) * 7 + c2], s);
  } else {
    for (int d = 0; d < 64; ++d)
      s = fmaf(Wo[c * 256 + h * 64 + d], Wv[(h * 64 + d) * 7 + c2], s);
  }
  AM[e] = s;
}

// ---------------------------------------------------------------------------
// Kernel 1: feas[t][c] = tanh( sum_f long_feature[t][f] * W_fc[c][f] )
// One wave handles 4 frames; lanes split F_DIM (32 floats each via 8 float4
// chunks). Memory-bound on long_feature (134 MB).
// ---------------------------------------------------------------------------
__global__ __launch_bounds__(256) void feas_kernel(
    const float* __restrict__ lf, const float* __restrict__ Wfc,
    float* __restrict__ feas) {
  const int lane = threadIdx.x & 63;
  const int wave = threadIdx.x >> 6;
  const int t0 = blockIdx.x * 16 + wave * 4;   // 4 frames per wave
  const float* lfp = lf + (size_t)t0 * FDIM;

  float acc[4][7];
#pragma unroll
  for (int fr = 0; fr < 4; ++fr)
#pragma unroll
    for (int c = 0; c < 7; ++c) acc[fr][c] = 0.0f;

  for (int chunk = 0; chunk < 8; ++chunk) {
    const int f = chunk * 256 + lane * 4;
    const float4 a0 = *(const float4*)(lfp + 0 * FDIM + f);
    const float4 a1 = *(const float4*)(lfp + 1 * FDIM + f);
    const float4 a2 = *(const float4*)(lfp + 2 * FDIM + f);
    const float4 a3 = *(const float4*)(lfp + 3 * FDIM + f);
#pragma unroll
    for (int c = 0; c < 7; ++c) {
      const float4 w = *(const float4*)(Wfc + c * FDIM + f);
      acc[0][c] = fmaf(a0.x, w.x, fmaf(a0.y, w.y, fmaf(a0.z, w.z, fmaf(a0.w, w.w, acc[0][c]))));
      acc[1][c] = fmaf(a1.x, w.x, fmaf(a1.y, w.y, fmaf(a1.z, w.z, fmaf(a1.w, w.w, acc[1][c]))));
      acc[2][c] = fmaf(a2.x, w.x, fmaf(a2.y, w.y, fmaf(a2.z, w.z, fmaf(a2.w, w.w, acc[2][c]))));
      acc[3][c] = fmaf(a3.x, w.x, fmaf(a3.y, w.y, fmaf(a3.z, w.z, fmaf(a3.w, w.w, acc[3][c]))));
    }
  }

#pragma unroll
  for (int fr = 0; fr < 4; ++fr) {
#pragma unroll
    for (int c = 0; c < 7; ++c) {
      float v = acc[fr][c];
      for (int off = 32; off > 0; off >>= 1) v += __shfl_down(v, off, 64);
      if (lane == 0) feas[(size_t)(t0 + fr) * 7 + c] = tanhf(v);
    }
  }
}

// ---------------------------------------------------------------------------
// Kernel 2: per-frame attention (collapsed to 7x7 bilinear forms) + LN + FFN.
// One thread per frame; 64-thread blocks; feats tile (93 x 7) staged in LDS.
// Zero-padded frames (s<0) give score exactly 0 and V contribution 0,
// matching the reference's zero-padding semantics.
// ---------------------------------------------------------------------------
__global__ __launch_bounds__(64) void attn_kernel(
    const float* __restrict__ x,      // (7, T) : feats[t][c] = x[c*T + t]
    const float* __restrict__ feas,   // (T, 7)
    const float* __restrict__ AM,     // 392 floats
    const float* __restrict__ W1,     // (64, 7)
    const float* __restrict__ W2,     // (7, 64)
    const float* __restrict__ ln1g, const float* __restrict__ ln1b,
    const float* __restrict__ ln2g, const float* __restrict__ ln2b,
    float* __restrict__ out) {        // (T, 7)
  __shared__ float ft[93 * 7];
  const int t0 = blockIdx.x * 64;
  const int tid = threadIdx.x;

  // Stage feats rows [t0-29, t0+63] (93 rows x 7), zeros before frame 0.
  for (int c = 0; c < 7; ++c) {
    for (int i = tid; i < 93; i += 64) {
      const int s = t0 - 29 + i;
      ft[i * 7 + c] = (s >= 0) ? x[c * T_FRAMES + s] : 0.0f;
    }
  }
  __syncthreads();

  const int t = t0 + tid;
  float fe[7];
#pragma unroll
  for (int c = 0; c < 7; ++c) fe[c] = feas[(size_t)t * 7 + c];

  const float* frow = &ft[tid * 7];  // window row j is frow + j*7
  float outp[7] = {0, 0, 0, 0, 0, 0, 0};

#pragma unroll
  for (int h = 0; h < 4; ++h) {
    const float* Ah = AM + h * 49;
    const float* Mh = AM + 196 + h * 49;
    // qk[c2] = (1/8) * sum_c fe[c] * A_h[c][c2]
    float qk[7];
#pragma unroll
    for (int c2 = 0; c2 < 7; ++c2) {
      float s = 0.0f;
#pragma unroll
      for (int c = 0; c < 7; ++c) s = fmaf(fe[c], Ah[c * 7 + c2], s);
      qk[c2] = s * 0.125f;
    }
    // scores over the 30-window
    float sc[LQ];
    float m = -1e30f;
#pragma unroll
    for (int j = 0; j < LQ; ++j) {
      const float* r = frow + j * 7;
      float s = 0.0f;
#pragma unroll
      for (int c2 = 0; c2 < 7; ++c2) s = fmaf(qk[c2], r[c2], s);
      sc[j] = s;
      m = fmaxf(m, s);
    }
    // softmax + weighted sum of feats rows
    float sum = 0.0f;
    float wsum[7] = {0, 0, 0, 0, 0, 0, 0};
#pragma unroll
    for (int j = 0; j < LQ; ++j) {
      const float p = __expf(sc[j] - m);
      sum += p;
      const float* r = frow + j * 7;
#pragma unroll
      for (int c2 = 0; c2 < 7; ++c2) wsum[c2] = fmaf(p, r[c2], wsum[c2]);
    }
    const float inv = 1.0f / sum;
    // out += M_h @ wsum / sum
#pragma unroll
    for (int c = 0; c < 7; ++c) {
      float s = 0.0f;
#pragma unroll
      for (int c2 = 0; c2 < 7; ++c2) s = fmaf(Mh[c * 7 + c2], wsum[c2], s);
      outp[c] = fmaf(s, inv, outp[c]);
    }
  }

  // residual + LN1
  float v[7];
#pragma unroll
  for (int c = 0; c < 7; ++c) v[c] = outp[c] + fe[c];
  float mu = 0.0f;
#pragma unroll
  for (int c = 0; c < 7; ++c) mu += v[c];
  mu *= (1.0f / 7.0f);
  float var = 0.0f;
#pragma unroll
  for (int c = 0; c < 7; ++c) { const float d = v[c] - mu; var = fmaf(d, d, var); }
  var *= (1.0f / 7.0f);
  float rs = rsqrtf(var + 1e-5f);
  float o1[7];
#pragma unroll
  for (int c = 0; c < 7; ++c) o1[c] = (v[c] - mu) * rs * ln1g[c] + ln1b[c];

  // FFN: ff = relu(o1 @ W1^T) @ W2^T
  float ff[7] = {0, 0, 0, 0, 0, 0, 0};
  for (int k = 0; k < 64; ++k) {
    float hk = 0.0f;
#pragma unroll
    for (int c = 0; c < 7; ++c) hk = fmaf(W1[k * 7 + c], o1[c], hk);
    hk = fmaxf(hk, 0.0f);
#pragma unroll
    for (int c = 0; c < 7; ++c) ff[c] = fmaf(W2[c * 64 + k], hk, ff[c]);
  }

  // residual + LN2
#pragma unroll
  for (int c = 0; c < 7; ++c) v[c] = ff[c] + o1[c];
  mu = 0.0f;
#pragma unroll
  for (int c = 0; c < 7; ++c) mu += v[c];
  mu *= (1.0f / 7.0f);
  var = 0.0f;
#pragma unroll
  for (int c = 0; c < 7; ++c) { const float d = v[c] - mu; var = fmaf(d, d, var); }
  var *= (1.0f / 7.0f);
  rs = rsqrtf(var + 1e-5f);
#pragma unroll
  for (int c = 0; c < 7; ++c)
    out[(size_t)t * 7 + c] = (v[c] - mu) * rs * ln2g[c] + ln2b[c];
}

// ---------------------------------------------------------------------------
extern "C" void kernel_launch(void* const* d_in, const int* in_sizes, int n_in,
                              void* d_out, int out_size, void* d_ws, size_t ws_size,
                              hipStream_t stream) {
  const float* x    = (const float*)d_in[0];   // (1, 7, T)
  const float* lf   = (const float*)d_in[1];   // (1, T, 2048)
  const float* Wfc  = (const float*)d_in[2];   // (7, 2048)
  const float* Wq   = (const float*)d_in[3];   // (256, 7)
  const float* Wk   = (const float*)d_in[4];   // (256, 7)
  const float* Wv   = (const float*)d_in[5];   // (256, 7)
  const float* Wo   = (const float*)d_in[6];   // (7, 256)
  const float* ln1g = (const float*)d_in[7];
  const float* ln1b = (const float*)d_in[8];
  const float* W1   = (const float*)d_in[9];   // (64, 7)
  const float* W2   = (const float*)d_in[10];  // (7, 64)
  const float* ln2g = (const float*)d_in[11];
  const float* ln2b = (const float*)d_in[12];
  float* out = (float*)d_out;

  float* feas = (float*)d_ws;                       // T*7 floats
  float* AM   = feas + (size_t)T_FRAMES * 7;        // 392 floats

  setup_kernel<<<1, 448, 0, stream>>>(Wq, Wk, Wv, Wo, AM);
  feas_kernel<<<T_FRAMES / 16, 256, 0, stream>>>(lf, Wfc, feas);
  attn_kernel<<<T_FRAMES / 64, 64, 0, stream>>>(x, feas, AM, W1, W2,
                                                ln1g, ln1b, ln2g, ln2b, out);
}

// Round 3
// 254.296 us; speedup vs baseline: 1.0227x; 1.0227x over previous
//
#include <hip/hip_runtime.h>
#include <math.h>

#define T_FRAMES 16384
#define FDIM 2048
#define LQ 30
#define FPB 16   // frames per block

// ---------------------------------------------------------------------------
// Kernel 0: precompute per-head 7x7 bilinear forms
//   A_h[c][c2] = sum_d W_q[h*64+d][c] * W_k[h*64+d][c2]
//   M_h[c][c2] = sum_d W_o[c][h*64+d] * W_v[h*64+d][c2]
// AM layout: [0..195] = A (h*49 + c*7 + c2), [196..391] = M
// ---------------------------------------------------------------------------
__global__ __launch_bounds__(448) void setup_kernel(
    const float* __restrict__ Wq, const float* __restrict__ Wk,
    const float* __restrict__ Wv, const float* __restrict__ Wo,
    float* __restrict__ AM) {
  const int e = threadIdx.x;
  if (e >= 392) return;
  const int which = e / 196;
  const int r = e % 196;
  const int h = r / 49;
  const int rr = r % 49;
  const int c = rr / 7;
  const int c2 = rr % 7;
  float s = 0.0f;
  if (which == 0) {
    for (int d = 0; d < 64; ++d)
      s = fmaf(Wq[(h * 64 + d) * 7 + c], Wk[(h * 64 + d) * 7 + c2], s);
  } else {
    for (int d = 0; d < 64; ++d)
      s = fmaf(Wo[c * 256 + h * 64 + d], Wv[(h * 64 + d) * 7 + c2], s);
  }
  AM[e] = s;
}

// ---------------------------------------------------------------------------
// Fused kernel: per block of 16 frames
//   phase 1: feas[t][c] = tanh(lf[t] . Wfc[c])  (wave w -> frames 4w..4w+3)
//   phase 2a: per (frame,head) lane: collapsed 7x7 attention -> head partials
//   phase 2b: per frame lane: head-sum + LN1 + FFN + LN2 -> out
// ---------------------------------------------------------------------------
__global__ __launch_bounds__(256) void fused_kernel(
    const float* __restrict__ lf,    // (T, 2048)
    const float* __restrict__ Wfc,   // (7, 2048)
    const float* __restrict__ x,     // (7, T)
    const float* __restrict__ AM,    // 392
    const float* __restrict__ W1,    // (64, 7)
    const float* __restrict__ W2,    // (7, 64)
    const float* __restrict__ ln1g, const float* __restrict__ ln1b,
    const float* __restrict__ ln2g, const float* __restrict__ ln2b,
    float* __restrict__ out) {       // (T, 7)
  __shared__ float feas_s[FPB][7];
  __shared__ float AM_s[392];
  __shared__ float ft[(FPB + LQ - 1) * 7];   // 45 rows x 7, row r = frame t0-29+r
  __shared__ float hpart[FPB][4][7];

  const int tid = threadIdx.x;
  const int lane = tid & 63;
  const int wave = tid >> 6;
  const int t0 = blockIdx.x * FPB;

  // stage AM (1.6 KB, L2-broadcast) — 392 > 256 threads, so strided loop!
  for (int i = tid; i < 392; i += 256) AM_s[i] = AM[i];
  // stage the feats window (45 rows x 7)
  for (int i = tid; i < (FPB + LQ - 1) * 7; i += 256) {
    const int row = i / 7, c = i % 7;
    const int s = t0 - (LQ - 1) + row;
    ft[i] = (s >= 0) ? x[c * T_FRAMES + s] : 0.0f;
  }

  // ---- phase 1: feas for 4 frames per wave ----
  const int tf = t0 + wave * 4;
  const float* lfp = lf + (size_t)tf * FDIM;
  float acc[4][7];
#pragma unroll
  for (int fr = 0; fr < 4; ++fr)
#pragma unroll
    for (int c = 0; c < 7; ++c) acc[fr][c] = 0.0f;

  for (int chunk = 0; chunk < 8; ++chunk) {
    const int f = chunk * 256 + lane * 4;
    const float4 a0 = *(const float4*)(lfp + 0 * FDIM + f);
    const float4 a1 = *(const float4*)(lfp + 1 * FDIM + f);
    const float4 a2 = *(const float4*)(lfp + 2 * FDIM + f);
    const float4 a3 = *(const float4*)(lfp + 3 * FDIM + f);
#pragma unroll
    for (int c = 0; c < 7; ++c) {
      const float4 w = *(const float4*)(Wfc + c * FDIM + f);
      acc[0][c] = fmaf(a0.x, w.x, fmaf(a0.y, w.y, fmaf(a0.z, w.z, fmaf(a0.w, w.w, acc[0][c]))));
      acc[1][c] = fmaf(a1.x, w.x, fmaf(a1.y, w.y, fmaf(a1.z, w.z, fmaf(a1.w, w.w, acc[1][c]))));
      acc[2][c] = fmaf(a2.x, w.x, fmaf(a2.y, w.y, fmaf(a2.z, w.z, fmaf(a2.w, w.w, acc[2][c]))));
      acc[3][c] = fmaf(a3.x, w.x, fmaf(a3.y, w.y, fmaf(a3.z, w.z, fmaf(a3.w, w.w, acc[3][c]))));
    }
  }

#pragma unroll
  for (int fr = 0; fr < 4; ++fr) {
#pragma unroll
    for (int c = 0; c < 7; ++c) {
      float v = acc[fr][c];
      for (int off = 32; off > 0; off >>= 1) v += __shfl_down(v, off, 64);
      if (lane == 0) feas_s[wave * 4 + fr][c] = tanhf(v);
    }
  }
  __syncthreads();

  // ---- phase 2a: (frame, head) lanes ----
  if (tid < FPB * 4) {
    const int f = tid >> 2;   // local frame
    const int h = tid & 3;    // head
    float fe[7];
#pragma unroll
    for (int c = 0; c < 7; ++c) fe[c] = feas_s[f][c];

    const float* Ah = AM_s + h * 49;
    const float* Mh = AM_s + 196 + h * 49;
    float qk[7];
#pragma unroll
    for (int c2 = 0; c2 < 7; ++c2) {
      float s = 0.0f;
#pragma unroll
      for (int c = 0; c < 7; ++c) s = fmaf(fe[c], Ah[c * 7 + c2], s);
      qk[c2] = s * 0.125f;
    }
    // window rows for frame f are ft[(f+j)*7 + c], j = 0..29
    const float* frow = &ft[f * 7];
    float sc[LQ];
    float m = -1e30f;
#pragma unroll
    for (int j = 0; j < LQ; ++j) {
      const float* r = frow + j * 7;
      float s = 0.0f;
#pragma unroll
      for (int c2 = 0; c2 < 7; ++c2) s = fmaf(qk[c2], r[c2], s);
      sc[j] = s;
      m = fmaxf(m, s);
    }
    float sum = 0.0f;
    float wsum[7] = {0, 0, 0, 0, 0, 0, 0};
#pragma unroll
    for (int j = 0; j < LQ; ++j) {
      const float p = __expf(sc[j] - m);
      sum += p;
      const float* r = frow + j * 7;
#pragma unroll
      for (int c2 = 0; c2 < 7; ++c2) wsum[c2] = fmaf(p, r[c2], wsum[c2]);
    }
    const float inv = 1.0f / sum;
#pragma unroll
    for (int c = 0; c < 7; ++c) {
      float s = 0.0f;
#pragma unroll
      for (int c2 = 0; c2 < 7; ++c2) s = fmaf(Mh[c * 7 + c2], wsum[c2], s);
      hpart[f][h][c] = s * inv;
    }
  }
  __syncthreads();

  // ---- phase 2b: per-frame epilogue ----
  if (tid < FPB) {
    const int f = tid;
    float v[7];
#pragma unroll
    for (int c = 0; c < 7; ++c)
      v[c] = feas_s[f][c] + hpart[f][0][c] + hpart[f][1][c] + hpart[f][2][c] + hpart[f][3][c];

    float mu = 0.0f;
#pragma unroll
    for (int c = 0; c < 7; ++c) mu += v[c];
    mu *= (1.0f / 7.0f);
    float var = 0.0f;
#pragma unroll
    for (int c = 0; c < 7; ++c) { const float d = v[c] - mu; var = fmaf(d, d, var); }
    var *= (1.0f / 7.0f);
    float rs = rsqrtf(var + 1e-5f);
    float o1[7];
#pragma unroll
    for (int c = 0; c < 7; ++c) o1[c] = (v[c] - mu) * rs * ln1g[c] + ln1b[c];

    float ff[7] = {0, 0, 0, 0, 0, 0, 0};
    for (int k = 0; k < 64; ++k) {
      float hk = 0.0f;
#pragma unroll
      for (int c = 0; c < 7; ++c) hk = fmaf(W1[k * 7 + c], o1[c], hk);
      hk = fmaxf(hk, 0.0f);
#pragma unroll
      for (int c = 0; c < 7; ++c) ff[c] = fmaf(W2[c * 64 + k], hk, ff[c]);
    }

#pragma unroll
    for (int c = 0; c < 7; ++c) v[c] = ff[c] + o1[c];
    mu = 0.0f;
#pragma unroll
    for (int c = 0; c < 7; ++c) mu += v[c];
    mu *= (1.0f / 7.0f);
    var = 0.0f;
#pragma unroll
    for (int c = 0; c < 7; ++c) { const float d = v[c] - mu; var = fmaf(d, d, var); }
    var *= (1.0f / 7.0f);
    rs = rsqrtf(var + 1e-5f);
    const int t = t0 + f;
#pragma unroll
    for (int c = 0; c < 7; ++c)
      out[(size_t)t * 7 + c] = (v[c] - mu) * rs * ln2g[c] + ln2b[c];
  }
}

// ---------------------------------------------------------------------------
extern "C" void kernel_launch(void* const* d_in, const int* in_sizes, int n_in,
                              void* d_out, int out_size, void* d_ws, size_t ws_size,
                              hipStream_t stream) {
  const float* x    = (const float*)d_in[0];   // (1, 7, T)
  const float* lf   = (const float*)d_in[1];   // (1, T, 2048)
  const float* Wfc  = (const float*)d_in[2];   // (7, 2048)
  const float* Wq   = (const float*)d_in[3];   // (256, 7)
  const float* Wk   = (const float*)d_in[4];   // (256, 7)
  const float* Wv   = (const float*)d_in[5];   // (256, 7)
  const float* Wo   = (const float*)d_in[6];   // (7, 256)
  const float* ln1g = (const float*)d_in[7];
  const float* ln1b = (const float*)d_in[8];
  const float* W1   = (const float*)d_in[9];   // (64, 7)
  const float* W2   = (const float*)d_in[10];  // (7, 64)
  const float* ln2g = (const float*)d_in[11];
  const float* ln2b = (const float*)d_in[12];
  float* out = (float*)d_out;

  float* AM = (float*)d_ws;   // 392 floats

  setup_kernel<<<1, 448, 0, stream>>>(Wq, Wk, Wv, Wo, AM);
  fused_kernel<<<T_FRAMES / FPB, 256, 0, stream>>>(
      lf, Wfc, x, AM, W1, W2, ln1g, ln1b, ln2g, ln2b, out);
}